// Round 10
// baseline (364.564 us; speedup 1.0000x reference)
//
#include <hip/hip_runtime.h>
#include <hip/hip_bf16.h>
#include <stdint.h>

#define B_  4
#define T_  300
#define U_  60
#define V_  1000
#define M_TOT (B_*T_*U_)   // 72000
#define MBCNT 282          // ceil(72000/256)
#define WK  1056           // padded W1t row stride (shorts)
#define PK  1040           // padded proj row stride (floats)

typedef __attribute__((ext_vector_type(8))) short short8;
typedef __attribute__((ext_vector_type(4))) float f32x4;
typedef __attribute__((ext_vector_type(4))) int int4v;

__device__ __forceinline__ short f2bf(float f) {
    union { float f; uint32_t u; } c; c.f = f;
    uint32_t u = c.u;
    uint32_t r = (u + 0x7FFFu + ((u >> 16) & 1u)) >> 16;
    return (short)r;
}

__device__ __forceinline__ float fast_tanh(float x) {
    float e = __expf(2.0f * x);
    float r = __builtin_amdgcn_rcpf(e + 1.0f);
    return 1.0f - 2.0f * r;
}

__device__ __forceinline__ void gl_lds16(const void* g, void* l) {
    __builtin_amdgcn_global_load_lds(
        (const __attribute__((address_space(1))) void*)g,
        (__attribute__((address_space(3))) void*)l, 16, 0, 0);
}

// ---------------- prep kernels ----------------

__global__ void transpose_cvt(const float* __restrict__ in, short* __restrict__ out,
                              int R, int C, int ostride) {
    __shared__ float tile[64][65];
    const int tx = threadIdx.x & 63, ty = threadIdx.x >> 6;
    const int r0 = blockIdx.y * 64, c0 = blockIdx.x * 64;
#pragma unroll
    for (int i = 0; i < 16; ++i) {
        int r = r0 + i * 4 + ty, c = c0 + tx;
        float v = 0.f;
        if (r < R && c < C) v = in[(long)r * C + c];
        tile[i * 4 + ty][tx] = v;
    }
    __syncthreads();
#pragma unroll
    for (int i = 0; i < 16; ++i) {
        int oc = c0 + i * 4 + ty;
        int orr = r0 + tx;
        out[(long)oc * ostride + orr] = f2bf(tile[tx][i * 4 + ty]);
    }
}

// W2 [1024 k][1000 v] -> half-tile units: unit(nb,t,h)=((nb*16+t)*2+h) of
// 128 rows x 64 k (16KB), plain row-major within unit.
__global__ void transpose_pack_w2(const float* __restrict__ in, short* __restrict__ out) {
    __shared__ float tile[64][65];
    const int tx = threadIdx.x & 63, ty = threadIdx.x >> 6;
    const int r0 = blockIdx.y * 64, c0 = blockIdx.x * 64;   // r=k, c=v
#pragma unroll
    for (int i = 0; i < 16; ++i) {
        int r = r0 + i * 4 + ty, c = c0 + tx;
        float v = 0.f;
        if (c < V_) v = in[(long)r * V_ + c];
        tile[i * 4 + ty][tx] = v;
    }
    __syncthreads();
#pragma unroll
    for (int i = 0; i < 16; ++i) {
        int oc = c0 + i * 4 + ty;       // v 0..1023
        int orr = r0 + tx;              // k 0..1023
        int nb = oc >> 8, pr = oc & 255, h = pr >> 7, rr = pr & 127;
        int t = orr >> 6, kk = orr & 63;
        out[(long)((nb * 16 + t) * 2 + h) * 8192 + rr * 64 + kk] =
            f2bf(tile[tx][i * 4 + ty]);
    }
}

// P[M][PK] = bf16(X[M][512]) @ W1t[k_off:k_off+512]^T (+ b1)
__global__ __launch_bounds__(256, 2) void proj_gemm(
        const float* __restrict__ X, int M, int k_off,
        const short* __restrict__ Wt,
        const float* __restrict__ b1,
        float* __restrict__ P)
{
    __shared__ short As[64 * 64];
    const int tid = threadIdx.x;
    const int lane = tid & 63;
    const int w = tid >> 6;
    const int wm = w >> 1, wn = w & 1;
    const int m0 = blockIdx.x * 64, n0 = blockIdx.y * 64;

    f32x4 acc[2][2] = {};
    for (int k0 = 0; k0 < 512; k0 += 64) {
#pragma unroll
        for (int c = 0; c < 2; ++c) {
            int lin = tid + 256 * c;
            int row = lin >> 3, k8 = lin & 7;
            int m = m0 + row;
            short vals[8];
            if (m < M) {
                const float* xp = X + (long)m * 512 + k0 + k8 * 8;
#pragma unroll
                for (int j = 0; j < 8; ++j) vals[j] = f2bf(xp[j]);
            } else {
#pragma unroll
                for (int j = 0; j < 8; ++j) vals[j] = 0;
            }
            int byte = row * 128 + k8 * 16;
            byte ^= (row & 7) << 4;
            *(int4v*)((char*)As + byte) = *(const int4v*)vals;
        }
        __syncthreads();
#pragma unroll
        for (int ks = 0; ks < 2; ++ks) {
            short8 af[2];
#pragma unroll
            for (int mf = 0; mf < 2; ++mf) {
                int row = wm * 32 + mf * 16 + (lane & 15);
                int byte = row * 128 + ks * 64 + (lane >> 4) * 16;
                byte ^= (row & 7) << 4;
                af[mf] = *(const short8*)((char*)As + byte);
            }
#pragma unroll
            for (int nf = 0; nf < 2; ++nf) {
                int h = n0 + wn * 32 + nf * 16 + (lane & 15);
                const short* bp = Wt + (long)h * WK + k_off + k0 + ks * 32 + (lane >> 4) * 8;
                short8 bfv = *(const short8*)bp;
#pragma unroll
                for (int mf = 0; mf < 2; ++mf)
                    acc[mf][nf] = __builtin_amdgcn_mfma_f32_16x16x32_bf16(af[mf], bfv, acc[mf][nf], 0, 0, 0);
            }
        }
        __syncthreads();
    }
#pragma unroll
    for (int mf = 0; mf < 2; ++mf)
#pragma unroll
        for (int nf = 0; nf < 2; ++nf) {
            int h = n0 + wn * 32 + nf * 16 + (lane & 15);
            float bb = b1 ? b1[h] : 0.f;
#pragma unroll
            for (int j = 0; j < 4; ++j) {
                int m = m0 + wm * 32 + mf * 16 + (lane >> 4) * 4 + j;
                if (m < M) P[(long)m * PK + h] = acc[mf][nf][j] + bb;
            }
        }
}

// ---------------- packed H: unit(mb,t,h)=((mb*16+t)*2+h), 128x64 (16KB) ------
__global__ __launch_bounds__(256) void hgen_pk(
        const float* __restrict__ encP, const float* __restrict__ decP,
        short* __restrict__ Hp)
{
    long idx = (long)blockIdx.x * 256 + threadIdx.x;
    int u = (int)(idx >> 10);
    int gi = (int)(idx & 1023);
    int mb = u >> 5, rem = u & 31, t = rem >> 1, h = rem & 1;
    int r = gi >> 3, kg = gi & 7;
    int m = mb * 256 + h * 128 + r;
    int k = t * 64 + kg * 8;
    short8 v = {};
    if (m < M_TOT) {
        int bt = m / U_;
        int uu = m - bt * U_;
        int b = m / (T_ * U_);
        const float* e = encP + (long)bt * PK + k;
        const float* d = decP + (long)(b * U_ + uu) * PK + k;
        f32x4 e0 = *(const f32x4*)(e), e1 = *(const f32x4*)(e + 4);
        f32x4 d0 = *(const f32x4*)(d), d1 = *(const f32x4*)(d + 4);
#pragma unroll
        for (int j = 0; j < 4; ++j) v[j]     = f2bf(fast_tanh(e0[j] + d0[j]));
#pragma unroll
        for (int j = 0; j < 4; ++j) v[4 + j] = f2bf(fast_tanh(e1[j] + d1[j]));
    }
    *(short8*)(Hp + (long)u * 8192 + gi * 8) = v;
}

// ---------------- main GEMM: 256x256, BK=64, 2-phase / 2-barrier tiles ------
// 8 waves (2m x 4n). Per K-tile: {stage 8 gl_lds(t+1); GATE vmcnt(8); barrier;
// 16 ds_read; lgkm(0); 32 MFMA (qm0); 8 ds_read; lgkm(0); 32 MFMA (qm1);
// barrier}. 2 barriers + 1 gate per tile (vs 8+3 in R9) -> 32 MFMA/barrier.
// Gate slack for a tile's fills = 1 full tile (~2600 cyc > HBM latency).
__global__ __launch_bounds__(512, 2) void gemm2p(
        const short* __restrict__ Hp,   // units (mb,t,h)
        const short* __restrict__ W2p,  // units (nb,t,h)
        const float* __restrict__ b2,
        float* __restrict__ out)        // [M_TOT][V_]
{
    __shared__ __align__(16) char lds[131072];

    const int tid = threadIdx.x;
    const int lane = tid & 63;
    const int w = tid >> 6;
    const int wm = w >> 2, wn = w & 3;
    const int l15 = lane & 15, ksel = lane >> 4;

    // bijective XCD swizzle (nwg = 1128 = 8*141)
    const int nwg = gridDim.x;
    int bid = blockIdx.x;
    int q = nwg >> 3, r = nwg & 7;
    int xcd = bid & 7, lq = bid >> 3;
    int wg = (xcd < r ? xcd * (q + 1) : r * (q + 1) + (xcd - r) * q) + lq;
    const int mb = wg >> 2, nb = wg & 3;

    // staging: thread -> 2 granules of each 16KB half-unit; source granule
    // permuted g = (tid&7) ^ (row&7)  (inverse of the ds_read XOR).
    const int rowA = tid >> 3;
    const int gA = (tid & 7) ^ (rowA & 7);
    const short* aSrc = Hp  + (long)mb * 262144 + rowA * 64 + gA * 8;
    const short* bSrc = W2p + (long)nb * 262144 + rowA * 64 + gA * 8;
    const int wq = w << 10;

#define ST_A(uidx_, roff_) do {                                              \
    gl_lds16(aSrc + (long)(uidx_) * 8192, (char*)lds + (roff_) + wq);        \
    gl_lds16(aSrc + (long)(uidx_) * 8192 + 4096,                             \
             (char*)lds + (roff_) + 8192 + wq);                              \
} while (0)
#define ST_B(uidx_, roff_) do {                                              \
    gl_lds16(bSrc + (long)(uidx_) * 8192, (char*)lds + (roff_) + wq);        \
    gl_lds16(bSrc + (long)(uidx_) * 8192 + 4096,                             \
             (char*)lds + (roff_) + 8192 + wq);                              \
} while (0)

    short8 af[4][2], bf0[2][2], bf1[2][2];
    f32x4 acc[8][4] = {};

#define RD_AF(d_, qm_) do {                                                  \
    _Pragma("unroll")                                                        \
    for (int mf = 0; mf < 4; ++mf) {                                         \
        const int rw_ = wm * 64 + mf * 16 + l15;                             \
        const char* bp_ = (const char*)lds + (d_) * 65536 + (qm_) * 16384    \
                          + rw_ * 128;                                       \
        const int sx_ = (rw_ & 7) << 4;                                      \
        af[mf][0] = *(const short8*)(bp_ + ((ksel * 16) ^ sx_));             \
        af[mf][1] = *(const short8*)(bp_ + ((64 + ksel * 16) ^ sx_));        \
    } } while (0)

#define RD_BF(d_, qn_, B_) do {                                              \
    _Pragma("unroll")                                                        \
    for (int nf = 0; nf < 2; ++nf) {                                         \
        const int rw_ = wn * 32 + nf * 16 + l15;                             \
        const char* bp_ = (const char*)lds + (d_) * 65536 + 32768            \
                          + (qn_) * 16384 + rw_ * 128;                       \
        const int sx_ = (rw_ & 7) << 4;                                      \
        B_[nf][0] = *(const short8*)(bp_ + ((ksel * 16) ^ sx_));             \
        B_[nf][1] = *(const short8*)(bp_ + ((64 + ksel * 16) ^ sx_));        \
    } } while (0)

#define MMQ(qm_) do {                                                        \
    __builtin_amdgcn_s_setprio(1);                                           \
    _Pragma("unroll")                                                        \
    for (int kh = 0; kh < 2; ++kh) {                                         \
        _Pragma("unroll")                                                    \
        for (int nf = 0; nf < 2; ++nf)                                       \
            _Pragma("unroll")                                                \
            for (int mf = 0; mf < 4; ++mf)                                   \
                acc[(qm_) * 4 + mf][nf] =                                    \
                    __builtin_amdgcn_mfma_f32_16x16x32_bf16(                 \
                        af[mf][kh], bf0[nf][kh], acc[(qm_) * 4 + mf][nf], 0, 0, 0); \
        _Pragma("unroll")                                                    \
        for (int nf = 0; nf < 2; ++nf)                                       \
            _Pragma("unroll")                                                \
            for (int mf = 0; mf < 4; ++mf)                                   \
                acc[(qm_) * 4 + mf][2 + nf] =                                \
                    __builtin_amdgcn_mfma_f32_16x16x32_bf16(                 \
                        af[mf][kh], bf1[nf][kh], acc[(qm_) * 4 + mf][2 + nf], 0, 0, 0); \
    }                                                                        \
    __builtin_amdgcn_s_setprio(0);                                           \
} while (0)

#define LGKM0 do {                                                           \
    asm volatile("s_waitcnt lgkmcnt(0)" ::: "memory");                       \
    __builtin_amdgcn_sched_barrier(0);                                       \
} while (0)

#define TILE2(t_, cur_, nxt_, GATE_) do {                                    \
    if ((t_) < 15) {                                                         \
        ST_A(((t_) + 1) * 2,     (nxt_) * 65536);                            \
        ST_A(((t_) + 1) * 2 + 1, (nxt_) * 65536 + 16384);                    \
        ST_B(((t_) + 1) * 2,     (nxt_) * 65536 + 32768);                    \
        ST_B(((t_) + 1) * 2 + 1, (nxt_) * 65536 + 49152);                    \
    }                                                                        \
    asm volatile("s_waitcnt vmcnt(" GATE_ ")" ::: "memory");                 \
    __builtin_amdgcn_s_barrier();                                            \
    __builtin_amdgcn_sched_barrier(0);                                       \
    RD_AF(cur_, 0); RD_BF(cur_, 0, bf0); RD_BF(cur_, 1, bf1);                \
    LGKM0;                                                                   \
    MMQ(0);                                                                  \
    RD_AF(cur_, 1);                                                          \
    LGKM0;                                                                   \
    MMQ(1);                                                                  \
    __builtin_amdgcn_s_barrier();                                            \
} while (0)

    // prologue: stage tile 0, full drain once
    ST_A(0, 0);
    ST_A(1, 16384);
    ST_B(0, 32768);
    ST_B(1, 49152);
    asm volatile("s_waitcnt vmcnt(0)" ::: "memory");
    __builtin_amdgcn_s_barrier();

#pragma unroll 1
    for (int t = 0; t < 15; ++t) {
        const int cur = t & 1;
        TILE2(t, cur, cur ^ 1, "8");
    }
    TILE2(15, 1, 0, "0");

    // epilogue: + b2, store fp32
#pragma unroll
    for (int qn = 0; qn < 2; ++qn)
#pragma unroll
        for (int nf = 0; nf < 2; ++nf) {
            int n = nb * 256 + qn * 128 + wn * 32 + nf * 16 + l15;
            if (n < V_) {
                float bv = b2[n];
#pragma unroll
                for (int qm = 0; qm < 2; ++qm)
#pragma unroll
                    for (int mf = 0; mf < 4; ++mf)
#pragma unroll
                        for (int j = 0; j < 4; ++j) {
                            int m = mb * 256 + qm * 128 + wm * 64 + mf * 16 + ksel * 4 + j;
                            if (m < M_TOT)
                                out[(long)m * V_ + n] = acc[qm * 4 + mf][qn * 2 + nf][j] + bv;
                        }
            }
        }
#undef ST_A
#undef ST_B
#undef RD_AF
#undef RD_BF
#undef MMQ
#undef LGKM0
#undef TILE2
}

// ---------------- fallback fused kernel (only if ws too small) ----------------
__global__ __launch_bounds__(512, 2) void joint_gemm(
        const float* __restrict__ encP, const float* __restrict__ decP,
        const short* __restrict__ W2t, const float* __restrict__ b2,
        float* __restrict__ out)
{
    __shared__ short As[2][64 * 64];
    const int tid = threadIdx.x;
    const int lane = tid & 63;
    const int w = tid >> 6;
    const int m0 = blockIdx.x * 64;
    const int n0 = blockIdx.y * 512;

    const int arow = tid >> 3;
    const int k8 = tid & 7;
    const int am = m0 + arow;
    const int bt = am / U_;
    const int u = am - bt * U_;
    const int bidx = am / (T_ * U_);
    const float* eptr = encP + (long)bt * PK + k8 * 8;
    const float* dptr = decP + (long)(bidx * U_ + u) * PK + k8 * 8;
    const int wbyte = (arow * 128 + k8 * 16) ^ ((arow & 7) << 4);

    f32x4 acc[4][4] = {};
    const short* bbase[4];
#pragma unroll
    for (int nf = 0; nf < 4; ++nf) {
        int n = n0 + w * 64 + nf * 16 + (lane & 15);
        bbase[nf] = W2t + (long)n * WK + (lane >> 4) * 8;
    }
    f32x4 e0 = *(const f32x4*)(eptr), e1 = *(const f32x4*)(eptr + 4);
    f32x4 d0 = *(const f32x4*)(dptr), d1 = *(const f32x4*)(dptr + 4);
    {
        short vals[8];
#pragma unroll
        for (int j = 0; j < 4; ++j) vals[j]     = f2bf(fast_tanh(e0[j] + d0[j]));
#pragma unroll
        for (int j = 0; j < 4; ++j) vals[4 + j] = f2bf(fast_tanh(e1[j] + d1[j]));
        *(int4v*)((char*)&As[0][0] + wbyte) = *(const int4v*)vals;
    }
    e0 = *(const f32x4*)(eptr + 64); e1 = *(const f32x4*)(eptr + 68);
    d0 = *(const f32x4*)(dptr + 64); d1 = *(const f32x4*)(dptr + 68);
    asm volatile("s_waitcnt lgkmcnt(0)" ::: "memory");
    __builtin_amdgcn_s_barrier();

#pragma unroll 1
    for (int t = 0; t < 16; ++t) {
        const int k0 = t * 64;
        short8 bfr[2][4];
#pragma unroll
        for (int ks = 0; ks < 2; ++ks)
#pragma unroll
            for (int nf = 0; nf < 4; ++nf)
                bfr[ks][nf] = *(const short8*)(bbase[nf] + k0 + ks * 32);
        if (t < 15) {
            short vals[8];
#pragma unroll
            for (int j = 0; j < 4; ++j) vals[j]     = f2bf(fast_tanh(e0[j] + d0[j]));
#pragma unroll
            for (int j = 0; j < 4; ++j) vals[4 + j] = f2bf(fast_tanh(e1[j] + d1[j]));
            *(int4v*)((char*)&As[(t & 1) ^ 1][0] + wbyte) = *(const int4v*)vals;
            if (t < 14) {
                e0 = *(const f32x4*)(eptr + k0 + 128); e1 = *(const f32x4*)(eptr + k0 + 132);
                d0 = *(const f32x4*)(dptr + k0 + 128); d1 = *(const f32x4*)(dptr + k0 + 132);
            }
        }
        const char* rb = (const char*)&As[t & 1][0];
#pragma unroll
        for (int ks = 0; ks < 2; ++ks) {
            short8 af[4];
#pragma unroll
            for (int mf = 0; mf < 4; ++mf) {
                int row = mf * 16 + (lane & 15);
                int byte = (row * 128 + ks * 64 + (lane >> 4) * 16) ^ ((row & 7) << 4);
                af[mf] = *(const short8*)(rb + byte);
            }
#pragma unroll
            for (int nf = 0; nf < 4; ++nf)
#pragma unroll
                for (int mf = 0; mf < 4; ++mf)
                    acc[mf][nf] = __builtin_amdgcn_mfma_f32_16x16x32_bf16(
                        af[mf], bfr[ks][nf], acc[mf][nf], 0, 0, 0);
        }
        if (t < 15) {
            asm volatile("s_waitcnt lgkmcnt(0)" ::: "memory");
            __builtin_amdgcn_s_barrier();
        }
    }
#pragma unroll
    for (int nf = 0; nf < 4; ++nf) {
        int n = n0 + w * 64 + nf * 16 + (lane & 15);
        float bv = (n < V_) ? b2[n] : 0.f;
#pragma unroll
        for (int mf = 0; mf < 4; ++mf)
#pragma unroll
            for (int j = 0; j < 4; ++j) {
                int m = m0 + mf * 16 + (lane >> 4) * 4 + j;
                if (n < V_)
                    out[(long)m * V_ + n] = acc[mf][nf][j] + bv;
            }
    }
}

// ---------------- launch ----------------
extern "C" void kernel_launch(void* const* d_in, const int* in_sizes, int n_in,
                              void* d_out, int out_size, void* d_ws, size_t ws_size,
                              hipStream_t stream) {
    const float* enc = (const float*)d_in[0];
    const float* dec = (const float*)d_in[1];
    const float* W1  = (const float*)d_in[2];
    const float* b1  = (const float*)d_in[3];
    const float* W2  = (const float*)d_in[4];
    const float* b2  = (const float*)d_in[5];
    float* out = (float*)d_out;

    char* ws = (char*)d_ws;
    size_t off = 0;
    short* W1t  = (short*)(ws + off); off += (size_t)1024 * WK * 2;
    short* W2p  = (short*)(ws + off); off += (size_t)1024 * WK * 2;
    float* encP = (float*)(ws + off); off += (size_t)1200 * PK * 4;
    float* decP = (float*)(ws + off); off += (size_t)240 * PK * 4;
    short* Hp   = (short*)(ws + off);
    size_t need = off + (size_t)MBCNT * 262144 * 2;

    transpose_cvt<<<dim3(16, 16), 256, 0, stream>>>(W1, W1t, 1024, 1024, WK);
    proj_gemm<<<dim3(19, 16), 256, 0, stream>>>(enc, 1200, 0,   W1t, nullptr, encP);
    proj_gemm<<<dim3(4, 16),  256, 0, stream>>>(dec, 240,  512, W1t, b1,      decP);

    if (ws_size >= need) {
        transpose_pack_w2<<<dim3(16, 16), 256, 0, stream>>>(W2, W2p);
        hgen_pk<<<MBCNT * 32 * 1024 / 256, 256, 0, stream>>>(encP, decP, Hp);
        gemm2p<<<MBCNT * 4, 512, 0, stream>>>(Hp, W2p, b2, out);
    } else {
        short* W2t = W2p;
        transpose_cvt<<<dim3(16, 16), 256, 0, stream>>>(W2, W2t, 1024, 1000, WK);
        joint_gemm<<<dim3(1125, 2), 512, 0, stream>>>(encP, decP, W2t, b2, out);
    }
}